// Round 8
// baseline (201.527 us; speedup 1.0000x reference)
//
#include <hip/hip_runtime.h>
#include <math.h>

// Problem constants (from reference): P=8 patch, N=16 slots, WS=32 window,
// B=8, C=12, H=W=512. ref_x/ref_y are runtime device scalars.
#define PP    8
#define NSEL  16
#define WSZ   32

// One block per (b,c). 256 threads.
__global__ __launch_bounds__(256) void patches_select_kernel(
    const float* __restrict__ d_re,
    const float* __restrict__ d_im,
    const int*   __restrict__ p_rx,
    const int*   __restrict__ p_ry,
    float*       __restrict__ out,
    int H, int W)
{
    const int bc  = blockIdx.x;      // b*C + c
    const int tid = threadIdx.x;

    const int rx = p_rx[0];
    const int ry = p_ry[0];
    const int wx0 = max(rx - WSZ / 2, 0);
    const int wx1 = min(rx + WSZ / 2, H);
    const int wy0 = max(ry - WSZ / 2, 0);
    const int wy1 = min(ry + WSZ / 2, W);
    const int Wh = wx1 - wx0;
    const int Ww = wy1 - wy0;
    const int Ph = Wh - PP + 1;
    const int Pw = Ww - PP + 1;
    const int M  = Ph * Pw;                 // <= 625
    const int Mpad = (M + 63) & ~63;        // <= 640 (64-padded), fits dists[1024]

    __shared__ float swin[WSZ][WSZ][2];  // window, re/im interleaved (8B pairs)
    __shared__ float sref[PP][PP][2];    // reference patch, interleaved
    __shared__ float dists[WSZ * WSZ];   // M distances + INF padding
    __shared__ int   selPK[NSEL];        // packed (pi<<8)|pj, or -1

    const size_t plane = (size_t)H * W;
    const float* baseR = d_re + (size_t)bc * plane;
    const float* baseI = d_im + (size_t)bc * plane;

    // ---- stage window into LDS (coalesced row reads); pow2 fast path ----
    if (Ww == WSZ) {
        for (int t = tid; t < Wh * WSZ; t += 256) {
            const int i = t >> 5, j = t & 31;
            const size_t g = (size_t)(wx0 + i) * W + (wy0 + j);
            swin[i][j][0] = baseR[g];
            swin[i][j][1] = baseI[g];
        }
    } else {
        for (int t = tid; t < Wh * Ww; t += 256) {
            const int i = t / Ww, j = t - i * Ww;
            const size_t g = (size_t)(wx0 + i) * W + (wy0 + j);
            swin[i][j][0] = baseR[g];
            swin[i][j][1] = baseI[g];
        }
    }
    // ---- stage reference patch (PP=8 pow2 -> shifts) ----
    for (int t = tid; t < PP * PP; t += 256) {
        const int i = t >> 3, j = t & 7;
        const size_t g = (size_t)(rx + i) * W + (ry + j);
        sref[i][j][0] = baseR[g];
        sref[i][j][1] = baseI[g];
    }
    // ---- pad dists[M..Mpad) with +INF (never a candidate: INF < curMax false) ----
    for (int t = M + tid; t < Mpad; t += 256) dists[t] = INFINITY;
    __syncthreads();

    // ---- distances: replicate numpy pairwise_sum(128) bit-exactly ----
    // Element order e = (dx*8 + dy)*2 + comp; r[j] accumulates stride-8 groups;
    // combine ((r0+r1)+(r2+r3))+((r4+r5)+(r6+r7)). Loads are order-free, so the
    // interleaved layout lets each (dx,dy) fetch its re/im pair as one b64 read;
    // the ADD order into each r[j] and the k-iteration order are unchanged ->
    // identical rounding.
    for (int m = tid; m < M; m += 256) {
        const int pi = m / Pw, pj = m - pi * Pw;
        float r[8];
#pragma unroll
        for (int j = 0; j < 8; ++j) r[j] = 0.0f;
        // group k covers e = 8k..8k+7  ->  dx = k>>1, dy base = (k&1)*4
#pragma unroll
        for (int k = 0; k < 16; ++k) {
            const int dx  = k >> 1;
            const int dyb = (k & 1) * 4;
#pragma unroll
            for (int dd = 0; dd < 4; ++dd) {
                const int dy = dyb + dd;
                const float2 wv = *reinterpret_cast<const float2*>(&swin[pi + dx][pj + dy][0]);
                const float2 rv = *reinterpret_cast<const float2*>(&sref[dx][dy][0]);
                const float dre = __fsub_rn(wv.x, rv.x);
                const float dim = __fsub_rn(wv.y, rv.y);
                // j = 2*dd + comp: same r[j] targets, same per-k order as before
                r[2 * dd + 0] = __fadd_rn(r[2 * dd + 0], __fmul_rn(dre, dre));
                r[2 * dd + 1] = __fadd_rn(r[2 * dd + 1], __fmul_rn(dim, dim));
            }
        }
        const float s0 = __fadd_rn(__fadd_rn(r[0], r[1]), __fadd_rn(r[2], r[3]));
        const float s1 = __fadd_rn(__fadd_rn(r[4], r[5]), __fadd_rn(r[6], r[7]));
        const float S  = __fadd_rn(s0, s1);
        // 0.5 * (S / 128): both exact power-of-two scalings -> S * (1/256) exact.
        dists[m] = S * (1.0f / 256.0f);
    }
    __syncthreads();

    // ---- sequential slot insertion, candidate-filtered (bit-exact) ----
    // Reference semantics: for each patch m in order, the FIRST slot with
    // nd > d_m is replaced. THEOREM: slot values only decrease, so patch m can
    // replace only if d_m < max(slots at time m), and max(slots) is
    // non-increasing. Per 64-patch batch we compute cand = ballot(d < curMax)
    // with curMax from the batch start -> a SUPERSET of the effective patches
    // (conservative: curMax only shrinks during the batch). Each candidate's
    // own ballot step re-validates (mask==0 -> no-op), so skipping
    // non-candidates is exact. Candidates are processed in ascending index
    // order (ffs over cand), preserving the reference scan order exactly.
    // Expected serial steps for random data: ~64 (first batch) + ~10-20/batch
    // vs 640 unconditional steps before.
    if (tid < 64) {
        float nd  = (tid < NSEL) ? 1e33f : -1.0f;  // lanes >=16 never match (d >= 0)
        int   mi  = -1;
        float curMax = 1e33f;                      // uniform upper bound on max slot
        for (int m0 = 0; m0 < Mpad; m0 += 64) {
            const float d = dists[m0 + tid];       // one patch per lane, coalesced
            unsigned long long cand = __ballot(d < curMax);
            bool changed = false;                  // uniform (mask is uniform)
            while (cand) {
                const int u = __ffsll(cand) - 1;   // next candidate, ascending
                cand &= (cand - 1);
                const float du = __shfl(d, u);     // uniform lane -> readlane bcast
                const unsigned long long mask = __ballot(nd > du);
                const int first = __ffsll(mask) - 1;   // -1 if mask==0: no-op
                if (tid == first) { nd = du; mi = m0 + u; }
                changed |= (mask != 0ull);
            }
            if (changed) {
                // refresh curMax = max over lanes 0..15 of nd (lanes >=16 hold -1;
                // xor-shuffles with s<16 stay within the 16-lane group)
                float t = nd;
#pragma unroll
                for (int s = 8; s; s >>= 1) t = fmaxf(t, __shfl_xor(t, s));
                curMax = __shfl(t, 0);
            }
        }
        if (tid < NSEL) {
            int pk = -1;
            if (mi >= 0) { const int pi = mi / Pw; pk = (pi << 8) | (mi - pi * Pw); }
            selPK[tid] = pk;   // one div per slot here, none in the output loop
        }
    }
    __syncthreads();

    // ---- write 16 selected patches: out[bc][slot][k][comp], k = dx*8+dy ----
    float* obase = out + (size_t)bc * (NSEL * PP * PP * 2);
    for (int t = tid; t < NSEL * PP * PP * 2; t += 256) {
        const int slot = t >> 7;          // /128
        const int rem  = t & 127;
        const int k    = rem >> 1;
        const int comp = rem & 1;
        const int pk   = selPK[slot];
        float v = 0.0f;                   // unfilled slot -> zeros (matches init ns)
        if (pk >= 0) {
            const int pi = pk >> 8, pj = pk & 255;
            const int dx = k >> 3, dy = k & 7;
            v = swin[pi + dx][pj + dy][comp];
        }
        obase[t] = v;
    }
}

extern "C" void kernel_launch(void* const* d_in, const int* in_sizes, int n_in,
                              void* d_out, int out_size, void* d_ws, size_t ws_size,
                              hipStream_t stream) {
    const float* d_re = (const float*)d_in[0];
    const float* d_im = (const float*)d_in[1];
    const int*   p_rx = (const int*)d_in[2];
    const int*   p_ry = (const int*)d_in[3];
    float* out = (float*)d_out;

    const int H = 512, W = 512;
    const int BC = in_sizes[0] / (H * W);   // 8*12 = 96

    patches_select_kernel<<<BC, 256, 0, stream>>>(d_re, d_im, p_rx, p_ry, out, H, W);
}

// Round 9
// 195.973 us; speedup vs baseline: 1.0283x; 1.0283x over previous
//
#include <hip/hip_runtime.h>
#include <math.h>

// Problem constants (from reference): P=8 patch, N=16 slots, WS=32 window,
// B=8, C=12, H=W=512. ref_x/ref_y are runtime device scalars.
#define PP    8
#define NSEL  16
#define WSZ   32

// One block per (b,c). 256 threads.
__global__ __launch_bounds__(256) void patches_select_kernel(
    const float* __restrict__ d_re,
    const float* __restrict__ d_im,
    const int*   __restrict__ p_rx,
    const int*   __restrict__ p_ry,
    float*       __restrict__ out,
    int H, int W)
{
    const int bc  = blockIdx.x;      // b*C + c
    const int tid = threadIdx.x;

    const int rx = p_rx[0];
    const int ry = p_ry[0];
    const int wx0 = max(rx - WSZ / 2, 0);
    const int wx1 = min(rx + WSZ / 2, H);
    const int wy0 = max(ry - WSZ / 2, 0);
    const int wy1 = min(ry + WSZ / 2, W);
    const int Wh = wx1 - wx0;
    const int Ww = wy1 - wy0;
    const int Ph = Wh - PP + 1;
    const int Pw = Ww - PP + 1;
    const int M  = Ph * Pw;                 // <= 625
    const int Mpad = (M + 63) & ~63;        // <= 640 (64-padded), fits dists[1024]

    __shared__ float swin[WSZ][WSZ][2];  // window, re/im interleaved (8B pairs)
    __shared__ float sref[PP][PP][2];    // reference patch, interleaved
    __shared__ float dists[WSZ * WSZ];   // M distances + INF padding
    __shared__ int   selPK[NSEL];        // packed (pi<<8)|pj, or -1

    const size_t plane = (size_t)H * W;
    const float* baseR = d_re + (size_t)bc * plane;
    const float* baseI = d_im + (size_t)bc * plane;

    // ---- stage window into LDS (coalesced row reads); pow2 fast path ----
    if (Ww == WSZ) {
        for (int t = tid; t < Wh * WSZ; t += 256) {
            const int i = t >> 5, j = t & 31;
            const size_t g = (size_t)(wx0 + i) * W + (wy0 + j);
            swin[i][j][0] = baseR[g];
            swin[i][j][1] = baseI[g];
        }
    } else {
        for (int t = tid; t < Wh * Ww; t += 256) {
            const int i = t / Ww, j = t - i * Ww;
            const size_t g = (size_t)(wx0 + i) * W + (wy0 + j);
            swin[i][j][0] = baseR[g];
            swin[i][j][1] = baseI[g];
        }
    }
    // ---- stage reference patch (PP=8 pow2 -> shifts) ----
    for (int t = tid; t < PP * PP; t += 256) {
        const int i = t >> 3, j = t & 7;
        const size_t g = (size_t)(rx + i) * W + (ry + j);
        sref[i][j][0] = baseR[g];
        sref[i][j][1] = baseI[g];
    }
    // ---- pad dists[M..Mpad) with +INF (never a candidate: INF < curMax false) ----
    for (int t = M + tid; t < Mpad; t += 256) dists[t] = INFINITY;
    __syncthreads();

    // ---- distances: replicate numpy pairwise_sum(128) bit-exactly ----
    // Element order e = (dx*8 + dy)*2 + comp; r[j] accumulates stride-8 groups;
    // combine ((r0+r1)+(r2+r3))+((r4+r5)+(r6+r7)). Loads are order-free, so the
    // interleaved layout lets each (dx,dy) fetch its re/im pair as one b64 read;
    // the ADD order into each r[j] and the k-iteration order are unchanged ->
    // identical rounding.
    for (int m = tid; m < M; m += 256) {
        const int pi = m / Pw, pj = m - pi * Pw;
        float r[8];
#pragma unroll
        for (int j = 0; j < 8; ++j) r[j] = 0.0f;
        // group k covers e = 8k..8k+7  ->  dx = k>>1, dy base = (k&1)*4
#pragma unroll
        for (int k = 0; k < 16; ++k) {
            const int dx  = k >> 1;
            const int dyb = (k & 1) * 4;
#pragma unroll
            for (int dd = 0; dd < 4; ++dd) {
                const int dy = dyb + dd;
                const float2 wv = *reinterpret_cast<const float2*>(&swin[pi + dx][pj + dy][0]);
                const float2 rv = *reinterpret_cast<const float2*>(&sref[dx][dy][0]);
                const float dre = __fsub_rn(wv.x, rv.x);
                const float dim = __fsub_rn(wv.y, rv.y);
                // j = 2*dd + comp: same r[j] targets, same per-k order as before
                r[2 * dd + 0] = __fadd_rn(r[2 * dd + 0], __fmul_rn(dre, dre));
                r[2 * dd + 1] = __fadd_rn(r[2 * dd + 1], __fmul_rn(dim, dim));
            }
        }
        const float s0 = __fadd_rn(__fadd_rn(r[0], r[1]), __fadd_rn(r[2], r[3]));
        const float s1 = __fadd_rn(__fadd_rn(r[4], r[5]), __fadd_rn(r[6], r[7]));
        const float S  = __fadd_rn(s0, s1);
        // 0.5 * (S / 128): both exact power-of-two scalings -> S * (1/256) exact.
        dists[m] = S * (1.0f / 256.0f);
    }
    __syncthreads();

    // ---- sequential slot insertion, candidate-filtered (bit-exact) ----
    // Reference semantics: for each patch m in order, the FIRST slot with
    // nd > d_m is replaced. THEOREM: a replacement happens iff d_m < max(slots),
    // and max(slots) is non-increasing. Per 64-patch batch, cand =
    // ballot(d < curMax) with batch-start curMax is a SUPERSET of the effective
    // patches; each candidate re-validates with the exact per-slot mask test
    // (mask==0 -> no-op), and candidates are processed in ascending index order
    // -> reference scan order preserved exactly.
    //
    // Perf notes vs previous version:
    //  * candidate value broadcast via v_readlane (SGPR, ~no latency) instead
    //    of __shfl (ds_bpermute: LDS round-trip on the serial chain)
    //  * curMax refresh via 16 unrolled readlanes + v_max (runs only on changed
    //    batches, <= 10 times) instead of ds_swizzle butterflies
    //  * next batch's d prefetched from LDS before candidate processing, so
    //    LDS latency stays off the dependent chain
    if (tid < 64) {
        float nd  = (tid < NSEL) ? 1e33f : -1.0f;  // lanes >=16 never match (d >= 0)
        int   mi  = -1;
        float curMax = 1e33f;                      // uniform upper bound on max slot
        float dcur = dists[tid];                   // batch 0 (Mpad >= 64)
        for (int m0 = 0; m0 < Mpad; m0 += 64) {
            const int nb = m0 + 64;
            // prefetch next batch (static LDS address -> issued early)
            const float dnxt = (nb < Mpad) ? dists[nb + tid] : INFINITY;
            unsigned long long cand = __ballot(dcur < curMax);
            bool changed = false;
            while (cand) {
                const int u = __ffsll(cand) - 1;   // next candidate, ascending
                cand &= (cand - 1);
                const float du = __int_as_float(
                    __builtin_amdgcn_readlane(__float_as_int(dcur), u));
                const unsigned long long mask = __ballot(nd > du);
                const int first = __ffsll(mask) - 1;   // -1 if mask==0: no-op
                if (tid == first) { nd = du; mi = m0 + u; }
                changed |= (mask != 0ull);
            }
            if (changed) {
                // curMax = max over lanes 0..15 of nd (uniform: readlane-only)
                float cm = -1.0f;
#pragma unroll
                for (int l = 0; l < NSEL; ++l) {
                    const float sl = __int_as_float(
                        __builtin_amdgcn_readlane(__float_as_int(nd), l));
                    cm = fmaxf(cm, sl);
                }
                curMax = cm;
            }
            dcur = dnxt;
        }
        if (tid < NSEL) {
            int pk = -1;
            if (mi >= 0) { const int pi = mi / Pw; pk = (pi << 8) | (mi - pi * Pw); }
            selPK[tid] = pk;   // one div per slot here, none in the output loop
        }
    }
    __syncthreads();

    // ---- write 16 selected patches: out[bc][slot][k][comp], k = dx*8+dy ----
    float* obase = out + (size_t)bc * (NSEL * PP * PP * 2);
    for (int t = tid; t < NSEL * PP * PP * 2; t += 256) {
        const int slot = t >> 7;          // /128
        const int rem  = t & 127;
        const int k    = rem >> 1;
        const int comp = rem & 1;
        const int pk   = selPK[slot];
        float v = 0.0f;                   // unfilled slot -> zeros (matches init ns)
        if (pk >= 0) {
            const int pi = pk >> 8, pj = pk & 255;
            const int dx = k >> 3, dy = k & 7;
            v = swin[pi + dx][pj + dy][comp];
        }
        obase[t] = v;
    }
}

extern "C" void kernel_launch(void* const* d_in, const int* in_sizes, int n_in,
                              void* d_out, int out_size, void* d_ws, size_t ws_size,
                              hipStream_t stream) {
    const float* d_re = (const float*)d_in[0];
    const float* d_im = (const float*)d_in[1];
    const int*   p_rx = (const int*)d_in[2];
    const int*   p_ry = (const int*)d_in[3];
    float* out = (float*)d_out;

    const int H = 512, W = 512;
    const int BC = in_sizes[0] / (H * W);   // 8*12 = 96

    patches_select_kernel<<<BC, 256, 0, stream>>>(d_re, d_im, p_rx, p_ry, out, H, W);
}